// Round 20
// baseline (128.350 us; speedup 1.0000x reference)
//
#include <hip/hip_runtime.h>

// Problem constants: B=8, M=N=256, D=512
#define USTR 192   // pair-planes per batch-dir: u = (row>>1) + lane, 0..190
typedef unsigned int u32;

// Raw HW transcendentals: v_exp_f32 is 2^x, v_log_f32 is log2(x).
#define EXP2F(x) __builtin_amdgcn_exp2f(x)
#define LOG2F(x) __builtin_amdgcn_logf(x)

// bf16 pack/unpack (round-to-nearest-even; values are positive finite).
__device__ __forceinline__ u32 bfr(float a) {        // rounded, bits in [31:16]
  u32 u = __float_as_uint(a);
  return u + 0x7FFFu + ((u >> 16) & 1u);
}
__device__ __forceinline__ u32 pk2(float a, float b) {
  return (bfr(a) >> 16) | (bfr(b) & 0xFFFF0000u);
}
__device__ __forceinline__ float lo2f(u32 d) { return __uint_as_float(d << 16); }
__device__ __forceinline__ float hi2f(u32 d) { return __uint_as_float(d & 0xFFFF0000u); }

// ---------------------------------------------------------------------------
// Kernel 1: inverse row norms.  rn = 1 / max(||row||, 1e-8)
// ---------------------------------------------------------------------------
__global__ void __launch_bounds__(256) norms_kernel(const float* __restrict__ x,
                                                    const float* __restrict__ y,
                                                    float* __restrict__ rnx,
                                                    float* __restrict__ rny) {
  int g = blockIdx.x * 4 + (threadIdx.x >> 6);
  int lane = threadIdx.x & 63;
  const float* src; float* dst; int row;
  if (g < 2048) { src = x; dst = rnx; row = g; }
  else          { src = y; dst = rny; row = g - 2048; }
  const float* p = src + (size_t)row * 512;
  float4 v0 = *(const float4*)(p + lane * 4);
  float4 v1 = *(const float4*)(p + 256 + lane * 4);
  float s = v0.x*v0.x + v0.y*v0.y + v0.z*v0.z + v0.w*v0.w
          + v1.x*v1.x + v1.y*v1.y + v1.z*v1.z + v1.w*v1.w;
#pragma unroll
  for (int o = 32; o > 0; o >>= 1) s += __shfl_xor(s, o, 64);
  if (lane == 0) dst[row] = 1.0f / fmaxf(sqrtf(s), 1e-8f);
}

// ---------------------------------------------------------------------------
// Kernel 2: cost GEMM, 32x64 tiles (256 blocks).  Output m = exp2(-cost*ig2)
// packed bf16x2, pair-plane layout, written twice (forward + index-reversed,
// BIT-IDENTICAL packing so the e_kernel's m-division cancels exactly):
//   forward  (batch-dir b):   plane u = v+l, lane l, dwords {v0v1,v2v3,w0w1,w2w3}
//   reversed (batch-dir 8+b): plane 190-u, lane 63-l, elements reversed
// ---------------------------------------------------------------------------
__global__ void __launch_bounds__(256) cost_gemm(const float* __restrict__ x,
                                                 const float* __restrict__ y,
                                                 const float* __restrict__ rnx,
                                                 const float* __restrict__ rny,
                                                 const float* __restrict__ gamma,
                                                 u32* __restrict__ mAllU) {
  int b = blockIdx.z, mt = blockIdx.y, nt = blockIdx.x;
  int m0 = mt * 32, n0 = nt * 64;
  __shared__ float Xs[16][36];
  __shared__ float Ys[16][68];
  int tid = threadIdx.x;
  int row = tid >> 2, cq = tid & 3;
  int tx = tid & 15, ty = tid >> 4;
  const float* xb = x + ((size_t)b * 256 + m0) * 512;
  const float* yb = y + ((size_t)b * 256 + n0) * 512;
  float acc[2][4] = {};
  for (int k0 = 0; k0 < 512; k0 += 16) {
    float4 xv;
    if (tid < 128) xv = *(const float4*)(xb + (size_t)row * 512 + k0 + cq * 4);
    float4 yv = *(const float4*)(yb + (size_t)row * 512 + k0 + cq * 4);
    __syncthreads();
    if (tid < 128) {
      Xs[cq*4+0][row] = xv.x; Xs[cq*4+1][row] = xv.y;
      Xs[cq*4+2][row] = xv.z; Xs[cq*4+3][row] = xv.w;
    }
    Ys[cq*4+0][row] = yv.x; Ys[cq*4+1][row] = yv.y;
    Ys[cq*4+2][row] = yv.z; Ys[cq*4+3][row] = yv.w;
    __syncthreads();
#pragma unroll
    for (int kk = 0; kk < 16; ++kk) {
      float a0 = Xs[kk][ty * 2 + 0];
      float a1 = Xs[kk][ty * 2 + 1];
      float4 bv = *(const float4*)(&Ys[kk][tx * 4]);
      float br[4] = {bv.x, bv.y, bv.z, bv.w};
#pragma unroll
      for (int c = 0; c < 4; ++c) {
        acc[0][c] += a0 * br[c];
        acc[1][c] += a1 * br[c];
      }
    }
  }
  float gv = fmaxf(fabsf(gamma[0]), 1e-4f);
  float ig2 = 1.4426950408889634f / gv;
  float rx[2], ry[4];
#pragma unroll
  for (int r = 0; r < 2; ++r) rx[r] = rnx[b * 256 + m0 + ty * 2 + r];
#pragma unroll
  for (int c = 0; c < 4; ++c) ry[c] = rny[b * 256 + n0 + tx * 4 + c];
  int l = nt * 16 + tx;                  // column-group lane
  int v = mt * 16 + ty;                  // row-pair index
  int u = v + l;                         // pair-plane index
  float4 stm[2];
#pragma unroll
  for (int r = 0; r < 2; ++r) {
    float c0 = (1.0f - acc[r][0] * rx[r] * ry[0]) * ig2;
    float c1 = (1.0f - acc[r][1] * rx[r] * ry[1]) * ig2;
    float c2 = (1.0f - acc[r][2] * rx[r] * ry[2]) * ig2;
    float c3 = (1.0f - acc[r][3] * rx[r] * ry[3]) * ig2;
    stm[r] = (float4){EXP2F(-c0), EXP2F(-c1), EXP2F(-c2), EXP2F(-c3)};
  }
  uint4 recF = {pk2(stm[0].x, stm[0].y), pk2(stm[0].z, stm[0].w),
                pk2(stm[1].x, stm[1].y), pk2(stm[1].z, stm[1].w)};
  *(uint4*)(mAllU + ((size_t)b * USTR + u) * 256 + l * 4) = recF;
  uint4 recR = {pk2(stm[1].w, stm[1].z), pk2(stm[1].y, stm[1].x),
                pk2(stm[0].w, stm[0].z), pk2(stm[0].y, stm[0].x)};
  *(uint4*)(mAllU + ((size_t)(8 + b) * USTR + (190 - u)) * 256 + (63 - l) * 4) = recR;
}

// ---------------------------------------------------------------------------
// Kernel 3: dual-direction p-pass, bf16 I/O.  Blocks 0-7: forward p on batch
// b; blocks 8-15: same recurrence on the reversed m = backward b-pass.  One
// wave per block; lane l owns cols 4l..4l+3; slot t: rows R=2(t-l), R+1 of
// plane u=t.  Recurrence carried in FULL f32 registers; only the m load and
// P store are bf16 (1 KB read + 1 KB write per slot -- R19 post-mortem:
// serial kernels are store-throughput bound at ~3.4 B/cyc/CU).  p = P*2^Q,
// Q constant per 8-slot epoch; E recovered later as p*b/(m*Z).
// ---------------------------------------------------------------------------
__global__ void __launch_bounds__(64, 1) pass_kernel(const u32* __restrict__ mAllU,
                                                     u32* __restrict__ pAllU,
                                                     float* __restrict__ QepAll,
                                                     const float* __restrict__ gamma,
                                                     float* __restrict__ dist_out) {
  int blk = blockIdx.x, l = threadIdx.x;
  int dir = blk >> 3, b = blk & 7;
  float gv = fmaxf(fabsf(gamma[0]), 1e-4f);
  float gl = gv * 0.6931471805599453f;      // R = q * gl
  const u32* mb = mAllU + (size_t)blk * USTR * 256 + l * 4;
  u32* pb = pAllU + (size_t)blk * USTR * 256 + l * 4;
  float* qe = QepAll + ((size_t)blk * 64 + l) * 24;
  float Pp0 = 0.f, Pp1 = 0.f, Pp2 = 0.f, Pp3 = 0.f;  // row R-1 (own, scaled)
  float bot0 = 0.f, bot1 = 0.f;   // my col-3 values of last pair (for lane l+1)
  int Q = 0;                       // lane scale: p = P * 2^Q
  float ucar = (l == 0) ? 1.0f : 0.f;  // p(R-1, 4l-1); origin seed p(-1,-1)=1
  uint4 A0, A1, A2, A3, A4, A5, A6, A7;
  uint4 A8, A9, A10, A11, A12, A13, A14, A15;
  auto loadC = [&](int t, uint4& buf) {
    int u = t > 190 ? 190 : t;
    buf = *(const uint4*)(mb + (size_t)u * 256);
  };
  auto body = [&](int t, const uint4 cc) {
    bool act = (unsigned)(t - l) <= 127u;
    float s0 = __shfl_up(bot0, 1);   // p(R,   4l-1) from lane l-1
    float s1 = __shfl_up(bot1, 1);   // p(R+1, 4l-1)
    int  liQ = __shfl_up(Q, 1);
    if (l == 0) { s0 = 0.f; s1 = 0.f; }
    else { int adj = liQ - Q; s0 = ldexpf(s0, adj); s1 = ldexpf(s1, adj); }
    float m0 = lo2f(cc.x), m1 = hi2f(cc.x), m2 = lo2f(cc.y), m3 = hi2f(cc.y);
    float m4 = lo2f(cc.z), m5 = hi2f(cc.z), m6 = lo2f(cc.w), m7 = hi2f(cc.w);
    // row R
    float v0 = m0 * (Pp0 + s0 + ucar);
    float v1 = m1 * (Pp1 + v0 + Pp0);
    float v2 = m2 * (Pp2 + v1 + Pp1);
    float v3 = m3 * (Pp3 + v2 + Pp2);
    // row R+1
    float w0 = m4 * (v0 + s1 + s0);
    float w1 = m5 * (v1 + w0 + v0);
    float w2 = m6 * (v2 + w1 + v1);
    float w3 = m7 * (v3 + w2 + v2);
    if (act) {
      uint4 st = {pk2(v0, v1), pk2(v2, v3), pk2(w0, w1), pk2(w2, w3)};
      *(uint4*)(pb + (size_t)t * 256) = st;
      Pp0 = w0; Pp1 = w1; Pp2 = w2; Pp3 = w3;
      ucar = s1; bot0 = v3; bot1 = w3;
      if (dir == 0 && l == 63 && t == 190)
        dist_out[b] = (-(float)Q - LOG2F(w3)) * gl;   // distance, off-loop
    }
  };
  auto renorm = [&](int tEnd) {
    if ((unsigned)(tEnd - l) <= 127u) {
      int e = (int)((__float_as_uint(Pp3) >> 23) & 255u) - 127;
      Pp0 = ldexpf(Pp0, -e); Pp1 = ldexpf(Pp1, -e);
      Pp2 = ldexpf(Pp2, -e); Pp3 = ldexpf(Pp3, -e);
      ucar = ldexpf(ucar, -e);
      bot0 = ldexpf(bot0, -e); bot1 = ldexpf(bot1, -e);
      Q += e;
    }
  };
  loadC(0, A0);  loadC(1, A1);  loadC(2, A2);  loadC(3, A3);
  loadC(4, A4);  loadC(5, A5);  loadC(6, A6);  loadC(7, A7);
  loadC(8, A8);  loadC(9, A9);  loadC(10, A10); loadC(11, A11);
  loadC(12, A12); loadC(13, A13); loadC(14, A14); loadC(15, A15);
  for (int it = 0; it < 12; ++it) {   // 12 x 16 = 192 slots; last live 190
    int s = it * 16;
    qe[2 * it] = (float)Q;
    body(s + 0, A0); loadC(s + 16, A0);
    body(s + 1, A1); loadC(s + 17, A1);
    body(s + 2, A2); loadC(s + 18, A2);
    body(s + 3, A3); loadC(s + 19, A3);
    body(s + 4, A4); loadC(s + 20, A4);
    body(s + 5, A5); loadC(s + 21, A5);
    body(s + 6, A6); loadC(s + 22, A6);
    body(s + 7, A7); loadC(s + 23, A7);
    renorm(s + 7);
    qe[2 * it + 1] = (float)Q;
    body(s + 8,  A8);  loadC(s + 24, A8);
    body(s + 9,  A9);  loadC(s + 25, A9);
    body(s + 10, A10); loadC(s + 26, A10);
    body(s + 11, A11); loadC(s + 27, A11);
    body(s + 12, A12); loadC(s + 28, A12);
    body(s + 13, A13); loadC(s + 29, A13);
    body(s + 14, A14); loadC(s + 30, A14);
    body(s + 15, A15); loadC(s + 31, A15);
    renorm(s + 15);
  }
}

// ---------------------------------------------------------------------------
// Kernel 4: posterior combine.  E[r][c] = p * b / (m * Z), Z = p(255,255).
// p = P*2^Qf, b = B*2^Qb, Z = Zp*2^Zq -> E = (P*B)/(M*Zp) * 2^(Qf+Qb-Zq).
// All P/B/M are bf16-packed; the stored m bits are identical to those used
// inside both passes, so the local m rounding cancels exactly.
// b(r,c) lives in the reversed output: plane 190-v-l, lane 63-l, half 1-rf,
// elements reversed.  Writes row-major float4 directly to d_out.
// ---------------------------------------------------------------------------
__global__ void __launch_bounds__(256) e_kernel(const u32* __restrict__ mAllU,
                                                const u32* __restrict__ pAllU,
                                                const float* __restrict__ QepAll,
                                                float* __restrict__ out) {
  int tid = blockIdx.x * 256 + threadIdx.x;   // = ((b*256 + r)*64 + l)
  int l = tid & 63;
  int r = (tid >> 6) & 255;
  int b = tid >> 14;
  int v = r >> 1, rf = r & 1;
  int uF = v + l;
  int uR = 190 - v - l;
  const u32* pF = pAllU + ((size_t)b * USTR + uF) * 256 + l * 4 + rf * 2;
  const u32* pR = pAllU + ((size_t)(8 + b) * USTR + uR) * 256 + (63 - l) * 4 + (1 - rf) * 2;
  const u32* mF = mAllU + ((size_t)b * USTR + uF) * 256 + l * 4 + rf * 2;
  u32 Px = pF[0], Py = pF[1];
  u32 Bx = pR[0], By = pR[1];
  u32 Mx = mF[0], My = mF[1];
  float P0 = lo2f(Px), P1 = hi2f(Px), P2 = lo2f(Py), P3 = hi2f(Py);
  float B0 = hi2f(By), B1 = lo2f(By), B2 = hi2f(Bx), B3 = lo2f(Bx);
  float M0 = lo2f(Mx), M1 = hi2f(Mx), M2 = lo2f(My), M3 = hi2f(My);
  float Qf = QepAll[((size_t)b * 64 + l) * 24 + (uF >> 3)];
  float Qb = QepAll[((size_t)(8 + b) * 64 + (63 - l)) * 24 + (uR >> 3)];
  float Zp = hi2f(pAllU[((size_t)b * USTR + 190) * 256 + 255]);
  float Zq = QepAll[((size_t)b * 64 + 63) * 24 + 23];
  int e = (int)(Qf + Qb - Zq);
  float inv = 1.0f / Zp;
  float4 o;
  o.x = ldexpf(P0 * B0 / M0 * inv, e);
  o.y = ldexpf(P1 * B1 / M1 * inv, e);
  o.z = ldexpf(P2 * B2 / M2 * inv, e);
  o.w = ldexpf(P3 * B3 / M3 * inv, e);
  *(float4*)(out + (size_t)b * 65536 + (size_t)r * 256 + 4 * l) = o;
}

// ---------------------------------------------------------------------------
// Workspace (4-byte units), ~6.4 MB:
//   rnx (2048) | rny (2048)
//   mAll  (16*192*256 dwords: bf16x2 potentials; dirs 0-7 fwd, 8-15 reversed)
//   pAll  (16*192*256 dwords: bf16x2 p-pass outputs, same layout)
//   QepAll (16*64*24 floats: per-block per-lane per-epoch scales)
// Alignment (E) and distance go straight into d_out.
// d_out: alignment [0 .. 524287], distance [524288 .. 524295].
// ---------------------------------------------------------------------------
extern "C" void kernel_launch(void* const* d_in, const int* in_sizes, int n_in,
                              void* d_out, int out_size, void* d_ws, size_t ws_size,
                              hipStream_t stream) {
  const float* x = (const float*)d_in[0];
  const float* y = (const float*)d_in[1];
  const float* gamma = (const float*)d_in[2];
  float* out = (float*)d_out;
  float* ws = (float*)d_ws;

  const size_t PMAT = (size_t)16 * USTR * 256;   // dwords
  float* rnx    = ws;
  float* rny    = ws + 2048;
  u32*   mAllU  = (u32*)(ws + 4096);
  u32*   pAllU  = mAllU + PMAT;
  float* QepAll = (float*)(pAllU + PMAT);

  norms_kernel<<<1024, 256, 0, stream>>>(x, y, rnx, rny);
  cost_gemm<<<dim3(4, 8, 8), 256, 0, stream>>>(x, y, rnx, rny, gamma, mAllU);
  pass_kernel<<<16, 64, 0, stream>>>(mAllU, pAllU, QepAll, gamma, out + 524288);
  e_kernel<<<512, 256, 0, stream>>>(mAllU, pAllU, QepAll, out);
}